// Round 15
// baseline (112.373 us; speedup 1.0000x reference)
//
#include <hip/hip_runtime.h>
#include <hip/hip_bf16.h>
#include <math.h>

#define BS   8
#define NPTS 2048
#define CCH  12      // channels per flow
#define NF   2       // flow dim
#define DIM  24      // NF*CCH, feats order: d = f*12 + c
#define KPAD 32      // MFMA K (24 + 8 zero pad)
#define KTOP 16
#define NWV  8       // waves per fused block (512 threads)
#define RPB  16      // rows per block (one m-tile)
#define CBUF 224     // survivor slots per row (E~64; P(overflow)~3e-7 total)
#define CBS  225     // padded stride
#define WVS  20      // padded row stride of per-wave C tile (16B-aligned)

#define NROWS    (BS * NPTS)
#define TGT_BASE (NROWS * KTOP * CCH)   // 3145728

typedef unsigned long long u64;
typedef unsigned int       u32;
typedef unsigned short     u16;
typedef __attribute__((ext_vector_type(8))) short short8;   // bf16x8 MFMA frag
typedef __attribute__((ext_vector_type(4))) float f32x4;

// ws layout (bytes)
#define WS_FEATS 0                                  // fp32 [NROWS][24]
#define WS_RAW   (NROWS * DIM * 4)                  // fp32 [NROWS][12]
#define WS_FHI   (WS_RAW + NROWS * CCH * 4)         // bf16 [NROWS][32]
#define WS_FLO   (WS_FHI + NROWS * KPAD * 2)        // bf16 [NROWS][32]

// Emulate np.linalg.norm(v) + 1e-8 in float32 exactly (numpy pairwise sum, n=24)
__device__ __forceinline__ float np_norm_den(const float* __restrict__ v)
{
#pragma clang fp contract(off)
    float s[DIM];
    #pragma unroll
    for (int d = 0; d < DIM; ++d) s[d] = v[d] * v[d];
    float r[8];
    #pragma unroll
    for (int j = 0; j < 8; ++j) r[j] = (s[j] + s[j + 8]) + s[j + 16];
    float res = ((r[0] + r[1]) + (r[2] + r[3])) + ((r[4] + r[5]) + (r[6] + r[7]));
    return sqrtf(res) + 1e-8f;
}

// Monotone float -> u32 (preserves total order for finite floats)
__device__ __forceinline__ u32 ordf(float f)
{
    u32 u = __float_as_uint(f);
    return ((int)u >= 0) ? (u | 0x80000000u) : ~u;
}

// round-to-nearest-even fp32 -> bf16 bits (finite inputs)
__device__ __forceinline__ u16 bf16_rne(float x)
{
    u32 bits = __float_as_uint(x);
    bits += 0x7fffu + ((bits >> 16) & 1u);
    return (u16)(bits >> 16);
}

// ---------------------------------------------------------------------------
// Kernel 0: normalize rows (numpy-exact fp32); write fp32 feats, bf16 hi/lo
// (K-padded to 32), raw flow slice, and the tgt_out output.  (unchanged)
// ---------------------------------------------------------------------------
__global__ __launch_bounds__(256) void prep_kernel(
    const float* __restrict__ x_c,     // [8][12][2][2048]
    const int*   __restrict__ flow_p,
    float*       __restrict__ feats,   // [NROWS][24] normalized fp32
    u16*         __restrict__ fhi,     // [NROWS][32] bf16 hi
    u16*         __restrict__ flo,     // [NROWS][32] bf16 lo
    float*       __restrict__ raw,     // [NROWS][12] raw flow slice
    float*       __restrict__ out)
{
    const int t = blockIdx.x * 256 + threadIdx.x;   // global row
    const int b = t >> 11;
    const int n = t & (NPTS - 1);
    const float* xb = x_c + (size_t)b * CCH * NF * NPTS;

    float v[DIM];
    float fn[DIM];
    {
#pragma clang fp contract(off)
        #pragma unroll
        for (int c = 0; c < CCH; ++c)
            #pragma unroll
            for (int f = 0; f < NF; ++f)
                v[f * CCH + c] = xb[(c * NF + f) * NPTS + n];

        const float den = np_norm_den(v);
        float* fo = feats + (size_t)t * DIM;
        #pragma unroll
        for (int d = 0; d < DIM; ++d) { fn[d] = v[d] / den; fo[d] = fn[d]; }
    }

    u16* ho = fhi + (size_t)t * KPAD;
    u16* lo = flo + (size_t)t * KPAD;
    #pragma unroll
    for (int d = 0; d < DIM; ++d) {
        const u16 hb = bf16_rne(fn[d]);
        const float hf = __uint_as_float((u32)hb << 16);
        ho[d] = hb;
        lo[d] = bf16_rne(fn[d] - hf);
    }
    #pragma unroll
    for (int d = DIM; d < KPAD; ++d) { ho[d] = 0; lo[d] = 0; }

    const int flow = flow_p[0];
    float* ro = raw + (size_t)t * CCH;
    #pragma unroll
    for (int c = 0; c < CCH; ++c) {
        const float xv = flow ? v[CCH + c] : v[c];
        ro[c] = xv;
        out[TGT_BASE + ((size_t)b * CCH + c) * NPTS + n] = xv;
    }
}

// 4-stage bitonic cleanup, desc (list must be bitonic)
#define CLEANUP_DESC(arr)                                         \
    _Pragma("unroll")                                             \
    for (int j_ = 8; j_ > 0; j_ >>= 1)                            \
        _Pragma("unroll")                                         \
        for (int i_ = 0; i_ < KTOP; ++i_) {                       \
            const int l_ = i_ | j_;                               \
            if (l_ > i_) {                                        \
                const float a_ = arr[i_], c_ = arr[l_];           \
                arr[i_] = fmaxf(a_, c_);                          \
                arr[l_] = fminf(a_, c_);                          \
            }                                                     \
        }

// merge two sorted-desc 16-lists (a, b) -> a = top-16 of union, sorted desc
#define MERGE_DESC(a, b)                                          \
    _Pragma("unroll")                                             \
    for (int i_ = 0; i_ < KTOP; ++i_)                             \
        a[i_] = fmaxf(a[i_], b[KTOP - 1 - i_]);                   \
    CLEANUP_DESC(a)

// ---------------------------------------------------------------------------
// Fused kernel: block = (b, 16-row chunk), 512 thr = 8 waves, 1024 blocks
// (4 blocks/CU x 8 waves = 8 waves/SIMD).
// MFMA split-bf16 approx dots (|approx-exact| <= eps ~1.2e-4).
// Pass 1 (subset, first 512 cands): wave w scans [w*64,+64) = 4 tiles with
// prefetch; per-lane 16 values -> bitonic sort DESC; shfl_xor(16,32) merges
// unify quad-copies; single-wave merge (wave 0: 1 LDS pairwise + 2 shfl
// merges) -> lb = subset 16th-largest; thr = lb - 8e-4 (same margin proof).
// Pass 2: all 2048 cands, compare in C-frag registers, sparse append.
// Exact rescue (bit-exact fp32 chain) + parallel rank-select + gather.
// ---------------------------------------------------------------------------
__global__ __launch_bounds__(512) void fused_topk_kernel(
    const float* __restrict__ feats,
    const u16*   __restrict__ fhi,
    const u16*   __restrict__ flo,
    const float* __restrict__ raw,
    float*       __restrict__ out)
{
    __shared__ union {
        float wval[NWV * 16 * WVS];   // 10 KiB: per-wave C tiles [w][cand16][row WVS]
        float vk[NWV * KTOP * 16];    // 8 KiB: wave lists [w][k][row16]
        u64   ckey[RPB * CBS];        // 28.1 KiB: survivors (aliases, disjoint in time)
    } sh;
    __shared__ float thr_s[RPB];
    __shared__ int   cnt[RPB];
    __shared__ int   sel[RPB][KTOP];

    const int tid  = threadIdx.x;
    const int lane = tid & 63;
    const int w    = __builtin_amdgcn_readfirstlane(tid >> 6);  // 0..7
    const int b     = blockIdx.x >> 7;
    const int chunk = blockIdx.x & 127;
    const int rb    = chunk * RPB;           // row base within batch
    const int p     = lane & 15;             // A-row / C-col index
    const int q     = lane >> 4;             // quad

    if (tid < RPB) cnt[tid] = 0;

    // A fragments: 16 rows (one m-tile), hi/lo
    short8 ahi, alo;
    {
        const size_t ae = ((size_t)(b * NPTS + rb + p)) * KPAD + q * 8;
        ahi = *(const short8*)(fhi + ae);
        alo = *(const short8*)(flo + ae);
    }

    float* wv = sh.wval + w * (16 * WVS);    // private C tile [cand][row]

    // ---- Pass 1 (subset: wave w scans [w*64, +64) = 4 tiles, prefetched) ----
    float vlist[KTOP];
    {
        size_t be_n = ((size_t)(b * NPTS + w * 64 + p)) * KPAD + q * 8;
        short8 nbhi = *(const short8*)(fhi + be_n);
        short8 nblo = *(const short8*)(flo + be_n);
        #pragma unroll
        for (int t = 0; t < 4; ++t) {
            const short8 bhi = nbhi, blo = nblo;
            if (t < 3) {                          // prefetch next tile
                const size_t be = ((size_t)(b * NPTS + w * 64 + (t + 1) * 16 + p)) * KPAD + q * 8;
                nbhi = *(const short8*)(fhi + be);
                nblo = *(const short8*)(flo + be);
            }
            f32x4 acc = {0.0f, 0.0f, 0.0f, 0.0f};
            acc = __builtin_amdgcn_mfma_f32_16x16x32_bf16(ahi, bhi, acc, 0, 0, 0);
            acc = __builtin_amdgcn_mfma_f32_16x16x32_bf16(ahi, blo, acc, 0, 0, 0);
            acc = __builtin_amdgcn_mfma_f32_16x16x32_bf16(alo, bhi, acc, 0, 0, 0);
            *(f32x4*)(wv + p * WVS + q * 4) = acc;   // [cand p][rows q*4+i]
            #pragma unroll
            for (int i = 0; i < 4; ++i)              // row p, cands q*4+i
                vlist[t * 4 + i] = wv[(q * 4 + i) * WVS + p];
        }
        // bitonic sort 16 DESCENDING (branchless)
        #pragma unroll
        for (int k = 2; k <= 16; k <<= 1)
            #pragma unroll
            for (int j = k >> 1; j > 0; j >>= 1)
                #pragma unroll
                for (int i = 0; i < 16; ++i) {
                    const int l = i | j;
                    if (l > i) {
                        const float a = vlist[i], c = vlist[l];
                        if ((i & k) == 0) { vlist[i] = fmaxf(a, c); vlist[l] = fminf(a, c); }
                        else              { vlist[i] = fminf(a, c); vlist[l] = fmaxf(a, c); }
                    }
                }
        // intra-wave merges: unify the 4 quad-copies of each row
        #pragma unroll
        for (int x = 16; x <= 32; x <<= 1) {
            float other[KTOP];
            #pragma unroll
            for (int k = 0; k < KTOP; ++k) other[k] = __shfl_xor(vlist[k], x);
            MERGE_DESC(vlist, other)
        }
    }

    __syncthreads();   // pass-1 tiles dead; alias as vk

    // ---- publish wave lists: vk[w][k][row], conflict-light ----
    if (q == 0) {
        #pragma unroll
        for (int k = 0; k < KTOP; ++k)
            sh.vk[(w * KTOP + k) * 16 + p] = vlist[k];
    }
    __syncthreads();

    // ---- single-wave merge of 8 lists per row (wave 0) ----
    if (w == 0) {
        const int r = lane >> 2;             // row 0..15
        const int g = lane & 3;              // list-pair 0..3
        float va[KTOP], vb[KTOP];
        #pragma unroll
        for (int k = 0; k < KTOP; ++k) {
            va[k] = sh.vk[((2 * g) * KTOP + k) * 16 + r];
            vb[k] = sh.vk[((2 * g + 1) * KTOP + k) * 16 + r];
        }
        MERGE_DESC(va, vb)
        #pragma unroll
        for (int x = 1; x <= 2; x <<= 1) {
            float other[KTOP];
            #pragma unroll
            for (int k = 0; k < KTOP; ++k) other[k] = __shfl_xor(va[k], x);
            MERGE_DESC(va, other)
        }
        if (g == 0) thr_s[r] = va[KTOP - 1] - 8e-4f;   // lb - 2*eps margin
    }
    __syncthreads();                          // thr ready; vk dead -> ckey usable

    // per-position thresholds for this lane's C-fragment rows (q*4+i)
    float thrv[4];
    #pragma unroll
    for (int i = 0; i < 4; ++i) thrv[i] = thr_s[q * 4 + i];

    // ---- Pass 2: all 2048 cands (wave w: [w*256,+256)), register compare ----
    {
        size_t be_n = ((size_t)(b * NPTS + w * 256 + p)) * KPAD + q * 8;
        short8 nbhi = *(const short8*)(fhi + be_n);
        short8 nblo = *(const short8*)(flo + be_n);
        for (int t = 0; t < 16; ++t) {
            const int cb0 = w * 256 + t * 16;
            const short8 bhi = nbhi, blo = nblo;
            if (t < 15) {                         // prefetch next tile
                const size_t be = ((size_t)(b * NPTS + cb0 + 16 + p)) * KPAD + q * 8;
                nbhi = *(const short8*)(fhi + be);
                nblo = *(const short8*)(flo + be);
            }
            f32x4 acc = {0.0f, 0.0f, 0.0f, 0.0f};
            acc = __builtin_amdgcn_mfma_f32_16x16x32_bf16(ahi, bhi, acc, 0, 0, 0);
            acc = __builtin_amdgcn_mfma_f32_16x16x32_bf16(ahi, blo, acc, 0, 0, 0);
            acc = __builtin_amdgcn_mfma_f32_16x16x32_bf16(alo, bhi, acc, 0, 0, 0);
            #pragma unroll
            for (int i = 0; i < 4; ++i) {
                if (acc[i] >= thrv[i]) {
                    const int r = q * 4 + i;            // row within chunk
                    const int pos = atomicAdd(&cnt[r], 1);
                    if (pos < CBUF)
                        sh.ckey[r * CBS + pos] = (u64)(u32)(cb0 + p);
                }
            }
        }
    }
    __syncthreads();

    // ---- exact rescue: bit-exact fp32 chain on survivors only ----
    {
        const int r = tid & 15;                  // row within chunk
        const float* fr = feats + (size_t)(b * NPTS + rb + r) * DIM;
        float rfn[DIM];
        #pragma unroll
        for (int d = 0; d < DIM; ++d) rfn[d] = fr[d];
        const int e = (cnt[r] < CBUF) ? cnt[r] : CBUF;
        for (int pos = tid >> 4; pos < e; pos += 32) {
            const int idx = (int)(u32)sh.ckey[r * CBS + pos];
            const float* cp = feats + (size_t)(b * NPTS + idx) * DIM;
            float acc = 0.0f;
            #pragma unroll
            for (int d = 0; d < DIM; ++d)
                acc = __builtin_fmaf(cp[d], rfn[d], acc);   // exact chain
            sh.ckey[r * CBS + pos] = ((u64)ordf(acc) << 32) | (u32)(2047 - idx);
        }
    }
    __syncthreads();

    // ---- parallel rank-select: 32 threads per row ----
    {
        const int L = tid >> 5;                  // 0..15
        const int g = tid & 31;
        const int e = (cnt[L] < CBUF) ? cnt[L] : CBUF;
        const u64* rowbuf = &sh.ckey[L * CBS];
        for (int pos = g; pos < e; pos += 32) {
            const u64 key = rowbuf[pos];
            int rank = 0;
            for (int p2 = 0; p2 < e; ++p2) rank += (rowbuf[p2] > key);
            if (rank < KTOP) sel[L][rank] = 2047 - (int)(key & 0xFFFFFFFFull);
        }
    }
    __syncthreads();

    // ---- gather: sx_c[b, n, k, c] = raw[(b*2048 + sel)*12 + c] ----
    const int rg = b * NPTS + rb;
    for (int e2 = tid; e2 < RPB * KTOP * CCH; e2 += 512) {
        const int L = e2 / (KTOP * CCH);
        const int r = e2 % (KTOP * CCH);
        const int k = r / CCH;
        const int c = r % CCH;
        out[((size_t)(rg + L) * KTOP + k) * CCH + c] =
            raw[((size_t)b * NPTS + sel[L][k]) * CCH + c];
    }
}

// ---------------------------------------------------------------------------
extern "C" void kernel_launch(void* const* d_in, const int* in_sizes, int n_in,
                              void* d_out, int out_size, void* d_ws, size_t ws_size,
                              hipStream_t stream)
{
    const float* x_c    = (const float*)d_in[0];
    const int*   flow_p = (const int*)d_in[1];
    float*       out    = (float*)d_out;

    float* feats = (float*)((char*)d_ws + WS_FEATS);
    float* raw   = (float*)((char*)d_ws + WS_RAW);
    u16*   fhi   = (u16*)  ((char*)d_ws + WS_FHI);
    u16*   flo   = (u16*)  ((char*)d_ws + WS_FLO);

    prep_kernel<<<NROWS / 256, 256, 0, stream>>>(x_c, flow_p, feats, fhi, flo, raw, out);
    fused_topk_kernel<<<BS * 128, 512, 0, stream>>>(feats, fhi, flo, raw, out);
}